// Round 1
// baseline (651.869 us; speedup 1.0000x reference)
//
#include <hip/hip_runtime.h>
#include <math.h>

#define N_GRAPHS 256
#define F_IN 12
#define HID 64
#define FC_DIM 140

// ---------- degree count ----------
__global__ void count_deg(const int* __restrict__ dst, int E, int* __restrict__ cnt) {
    int e = blockIdx.x * blockDim.x + threadIdx.x;
    if (e < E) atomicAdd(&cnt[dst[e]], 1);
}

__global__ void compute_dinv(const int* __restrict__ cnt, float* __restrict__ dinv, int N) {
    int i = blockIdx.x * blockDim.x + threadIdx.x;
    if (i < N) dinv[i] = rsqrtf((float)(cnt[i] + 1));  // +1 self-loop; always > 0
}

// ---------- exclusive scan (single block, hierarchical) ----------
__global__ void scan_cnt(const int* __restrict__ cnt, int* __restrict__ rowptr, int n) {
    __shared__ int wsum[16];
    int lane = threadIdx.x & 63;
    int wave = threadIdx.x >> 6;
    int base = 0;
    for (int start = 0; start < n; start += 1024 * 8) {
        int idx0 = start + threadIdx.x * 8;
        int v[8]; int s = 0;
#pragma unroll
        for (int k = 0; k < 8; k++) { int i = idx0 + k; v[k] = (i < n) ? cnt[i] : 0; s += v[k]; }
        int incl = s;
#pragma unroll
        for (int off = 1; off < 64; off <<= 1) {
            int t = __shfl_up(incl, off, 64);
            if (lane >= off) incl += t;
        }
        if (lane == 63) wsum[wave] = incl;
        __syncthreads();
        int woff = 0, total = 0;
#pragma unroll
        for (int w = 0; w < 16; w++) { int xv = wsum[w]; total += xv; if (w < wave) woff += xv; }
        int run = base + woff + (incl - s);
#pragma unroll
        for (int k = 0; k < 8; k++) { int i = idx0 + k; if (i < n) rowptr[i] = run; run += v[k]; }
        base += total;
        __syncthreads();
    }
    if (threadIdx.x == 0) rowptr[n] = base;
}

// ---------- CSR scatter ----------
__global__ void scatter_edges(const int* __restrict__ src, const int* __restrict__ dst, int E,
                              const int* __restrict__ rowptr, int* __restrict__ cursor,
                              int* __restrict__ ssrc) {
    int e = blockIdx.x * blockDim.x + threadIdx.x;
    if (e < E) {
        int d = dst[e];
        int pos = rowptr[d] + atomicAdd(&cursor[d], 1);
        ssrc[pos] = src[e];
    }
}

// ---------- layer-1 aggregation of raw x (12 features); 16 lanes/node ----------
__global__ void agg_x(const float* __restrict__ x, const float* __restrict__ dinv,
                      const int* __restrict__ rowptr, const int* __restrict__ ssrc,
                      float* __restrict__ aggx, int N) {
    int t = blockIdx.x * blockDim.x + threadIdx.x;
    int node = t >> 4;
    int f = t & 15;
    if (node >= N) return;
    float di = dinv[node];
    int p0 = rowptr[node], p1 = rowptr[node + 1];
    float acc = 0.f;
    for (int p = p0; p < p1; ++p) {
        int j = ssrc[p];
        float dj = dinv[j];
        if (f < F_IN) acc += dj * x[j * F_IN + f];
    }
    if (f < F_IN) aggx[node * F_IN + f] = di * acc + di * di * x[node * F_IN + f];
}

// ---------- h1 = tanh(aggx @ W1 + b1); 4 nodes/block ----------
__global__ void mm1(const float* __restrict__ aggx, const float* __restrict__ W1,
                    const float* __restrict__ b1, float* __restrict__ h1, int N) {
    __shared__ float w[F_IN * HID];
    __shared__ float rows[4][F_IN];
    int tid = threadIdx.x;
    for (int idx = tid; idx < F_IN * HID; idx += 256) w[idx] = W1[idx];
    int local = tid >> 6, f = tid & 63;
    int node = blockIdx.x * 4 + local;
    if (node < N && f < F_IN) rows[local][f] = aggx[node * F_IN + f];
    __syncthreads();
    if (node < N) {
        float acc = b1[f];
#pragma unroll
        for (int k = 0; k < F_IN; k++) acc += rows[local][k] * w[k * HID + f];
        h1[node * HID + f] = tanhf(acc);
    }
}

// ---------- layer-2 aggregation of h (64 features); 1 wave/node ----------
__global__ void agg_h(const float* __restrict__ h, const float* __restrict__ dinv,
                      const int* __restrict__ rowptr, const int* __restrict__ ssrc,
                      float* __restrict__ out, int N) {
    int t = blockIdx.x * blockDim.x + threadIdx.x;
    int node = t >> 6;
    int f = t & 63;
    if (node >= N) return;
    float di = dinv[node];
    int p0 = rowptr[node], p1 = rowptr[node + 1];
    float acc = 0.f;
    for (int p = p0; p < p1; ++p) {
        int j = ssrc[p];
        acc += dinv[j] * h[j * HID + f];
    }
    out[node * HID + f] = di * acc + di * di * h[node * HID + f];
}

// ---------- buf = tanh(buf @ W2 + b2) in-place (rows staged in LDS) ----------
__global__ void mm2_inplace(float* __restrict__ buf, const float* __restrict__ W2,
                            const float* __restrict__ b2, int N) {
    __shared__ float w[HID * HID];
    __shared__ float rows[4][HID];
    int tid = threadIdx.x;
    for (int idx = tid; idx < HID * HID; idx += 256) w[idx] = W2[idx];
    int local = tid >> 6, f = tid & 63;
    int node = blockIdx.x * 4 + local;
    if (node < N) rows[local][f] = buf[node * HID + f];
    __syncthreads();
    if (node < N) {
        float acc = b2[f];
#pragma unroll
        for (int k = 0; k < HID; k++) acc += rows[local][k] * w[k * HID + f];
        buf[node * HID + f] = tanhf(acc);
    }
}

// ---------- pooled[g] = sum over nodes in graph g of [x, h1, h2] ----------
__device__ __forceinline__ int lower_bound_i(const int* b, int n, int v) {
    int lo = 0, hi = n;
    while (lo < hi) { int m = (lo + hi) >> 1; if (b[m] < v) lo = m + 1; else hi = m; }
    return lo;
}

__global__ void pool_kernel(const float* __restrict__ x, const float* __restrict__ h1,
                            const float* __restrict__ h2, const int* __restrict__ batch,
                            float* __restrict__ pooled, int N) {
    int g = blockIdx.x >> 3;
    int sub = blockIdx.x & 7;
    int start = lower_bound_i(batch, N, g);
    int end = lower_bound_i(batch, N, g + 1);
    int len = end - start;
    int per = (len + 7) >> 3;
    int s = start + sub * per;
    int e = min(s + per, end);
    int f = threadIdx.x;
    if (f >= FC_DIM) return;
    const float* base; int stride, off;
    if (f < F_IN)            { base = x;  stride = F_IN; off = f; }
    else if (f < F_IN + HID) { base = h1; stride = HID;  off = f - F_IN; }
    else                     { base = h2; stride = HID;  off = f - F_IN - HID; }
    float acc = 0.f;
    for (int node = s; node < e; ++node) acc += base[node * stride + off];
    if (s < e) atomicAdd(&pooled[g * FC_DIM + f], acc);
}

// ---------- out = pooled @ fc_W^T + fc_b ----------
__global__ void fc_kernel(const float* __restrict__ pooled, const float* __restrict__ fcW,
                          const float* __restrict__ fcb, float* __restrict__ out) {
    __shared__ float p[FC_DIM];
    int g = blockIdx.x, tid = threadIdx.x;
    if (tid < FC_DIM) p[tid] = pooled[g * FC_DIM + tid];
    __syncthreads();
    if (tid < FC_DIM) {
        float acc = fcb[tid];
        for (int k = 0; k < FC_DIM; k++) acc += p[k] * fcW[tid * FC_DIM + k];
        out[g * FC_DIM + tid] = acc;
    }
}

extern "C" void kernel_launch(void* const* d_in, const int* in_sizes, int n_in,
                              void* d_out, int out_size, void* d_ws, size_t ws_size,
                              hipStream_t stream) {
    const float* x   = (const float*)d_in[0];
    const float* W1  = (const float*)d_in[1];
    const float* b1  = (const float*)d_in[2];
    const float* W2  = (const float*)d_in[3];
    const float* b2  = (const float*)d_in[4];
    const float* fcW = (const float*)d_in[5];
    const float* fcb = (const float*)d_in[6];
    const int*   ei  = (const int*)d_in[7];
    const int*   batch = (const int*)d_in[8];
    const int N = in_sizes[8];
    const int E = in_sizes[7] / 2;
    const int* src = ei;
    const int* dst = ei + E;

    char* ws = (char*)d_ws;
    size_t off = 0;
    auto alloc = [&](size_t elems) -> void* { void* p = ws + off; off += elems * 4; return p; };
    int*   cnt    = (int*)alloc(N);
    float* dinv   = (float*)alloc(N);
    int*   rowptr = (int*)alloc((size_t)N + 1);
    int*   cursor = (int*)alloc(N);
    int*   ssrc   = (int*)alloc(E);
    float* aggx   = (float*)alloc((size_t)N * F_IN);
    float* h1     = (float*)alloc((size_t)N * HID);
    float* buf2   = (float*)alloc((size_t)N * HID);   // agg1 then h2 (in-place)
    float* pooled = (float*)alloc((size_t)N_GRAPHS * FC_DIM);
    float* out = (float*)d_out;

    hipMemsetAsync(cnt, 0, (size_t)N * 4, stream);
    hipMemsetAsync(cursor, 0, (size_t)N * 4, stream);
    hipMemsetAsync(pooled, 0, (size_t)N_GRAPHS * FC_DIM * 4, stream);

    count_deg<<<(E + 255) / 256, 256, 0, stream>>>(dst, E, cnt);
    compute_dinv<<<(N + 255) / 256, 256, 0, stream>>>(cnt, dinv, N);
    scan_cnt<<<1, 1024, 0, stream>>>(cnt, rowptr, N);
    scatter_edges<<<(E + 255) / 256, 256, 0, stream>>>(src, dst, E, rowptr, cursor, ssrc);
    agg_x<<<((size_t)N * 16 + 255) / 256, 256, 0, stream>>>(x, dinv, rowptr, ssrc, aggx, N);
    mm1<<<(N + 3) / 4, 256, 0, stream>>>(aggx, W1, b1, h1, N);
    agg_h<<<(N + 3) / 4, 256, 0, stream>>>(h1, dinv, rowptr, ssrc, buf2, N);
    mm2_inplace<<<(N + 3) / 4, 256, 0, stream>>>(buf2, W2, b2, N);
    pool_kernel<<<N_GRAPHS * 8, 192, 0, stream>>>(x, h1, buf2, batch, pooled, N);
    fc_kernel<<<N_GRAPHS, 192, 0, stream>>>(pooled, fcW, fcb, out);
}

// Round 2
// 585.155 us; speedup vs baseline: 1.1140x; 1.1140x over previous
//
#include <hip/hip_runtime.h>
#include <hip/hip_fp16.h>
#include <math.h>

#define N_GRAPHS 256
#define F_IN 12
#define HID 64
#define FC_DIM 140

// ---------- degree count ----------
__global__ void count_deg(const int* __restrict__ dst, int E, int* __restrict__ cnt) {
    int e = blockIdx.x * blockDim.x + threadIdx.x;
    if (e < E) atomicAdd(&cnt[dst[e]], 1);
}

// ---------- dinv + prescaled half x table: xs[i] = dinv[i]*x[i] ----------
__global__ void dinv_xs(const int* __restrict__ cnt, const float* __restrict__ x,
                        float* __restrict__ dinv, __half* __restrict__ xs, int N) {
    int t = blockIdx.x * blockDim.x + threadIdx.x;
    int node = t >> 4, f = t & 15;
    if (node >= N) return;
    float di = rsqrtf((float)(cnt[node] + 1));  // +1 self-loop
    if (f == 0) dinv[node] = di;
    if (f < F_IN) xs[node * F_IN + f] = __float2half(di * x[node * F_IN + f]);
}

// ---------- exclusive scan (single block, hierarchical) ----------
__global__ void scan_cnt(const int* __restrict__ cnt, int* __restrict__ rowptr, int n) {
    __shared__ int wsum[16];
    int lane = threadIdx.x & 63;
    int wave = threadIdx.x >> 6;
    int base = 0;
    for (int start = 0; start < n; start += 1024 * 8) {
        int idx0 = start + threadIdx.x * 8;
        int v[8]; int s = 0;
#pragma unroll
        for (int k = 0; k < 8; k++) { int i = idx0 + k; v[k] = (i < n) ? cnt[i] : 0; s += v[k]; }
        int incl = s;
#pragma unroll
        for (int off = 1; off < 64; off <<= 1) {
            int t = __shfl_up(incl, off, 64);
            if (lane >= off) incl += t;
        }
        if (lane == 63) wsum[wave] = incl;
        __syncthreads();
        int woff = 0, total = 0;
#pragma unroll
        for (int w = 0; w < 16; w++) { int xv = wsum[w]; total += xv; if (w < wave) woff += xv; }
        int run = base + woff + (incl - s);
#pragma unroll
        for (int k = 0; k < 8; k++) { int i = idx0 + k; if (i < n) rowptr[i] = run; run += v[k]; }
        base += total;
        __syncthreads();
    }
    if (threadIdx.x == 0) rowptr[n] = base;
}

// ---------- CSR scatter (consumes cnt as cursor via atomicSub) ----------
__global__ void scatter_edges(const int* __restrict__ src, const int* __restrict__ dst, int E,
                              const int* __restrict__ rowptr, int* __restrict__ cnt,
                              int* __restrict__ ssrc) {
    int e = blockIdx.x * blockDim.x + threadIdx.x;
    if (e < E) {
        int d = dst[e];
        int pos = rowptr[d] + (atomicSub(&cnt[d], 1) - 1);
        ssrc[pos] = src[e];
    }
}

// ---------- layer-1 aggregation of xs (12 halves/row); 16 lanes/node ----------
__global__ void agg_x(const __half* __restrict__ xs, const float* __restrict__ dinv,
                      const int* __restrict__ rowptr, const int* __restrict__ ssrc,
                      float* __restrict__ aggx, int N) {
    int t = blockIdx.x * blockDim.x + threadIdx.x;
    int node = t >> 4;
    int f = t & 15;
    int gbase = (threadIdx.x & 63) & ~15;  // lane base of this 16-group
    if (node >= N) return;
    float di = dinv[node];
    int p0 = rowptr[node], p1 = rowptr[node + 1];
    float acc = 0.f;
    for (int base = p0; base < p1; base += 16) {
        int m = min(16, p1 - base);
        int jl = (base + f < p1) ? ssrc[base + f] : 0;
        for (int i = 0; i < m; ++i) {
            int j = __shfl(jl, gbase + i, 64);
            if (f < F_IN) acc += __half2float(xs[j * F_IN + f]);
        }
    }
    if (f < F_IN) {
        acc += __half2float(xs[node * F_IN + f]);  // self-loop (already dinv-scaled)
        aggx[node * F_IN + f] = di * acc;
    }
}

// ---------- h1 = tanh(aggx @ W1 + b1); writes float h1 + half prescaled h1s ----------
__global__ void mm1(const float* __restrict__ aggx, const float* __restrict__ W1,
                    const float* __restrict__ b1, const float* __restrict__ dinv,
                    float* __restrict__ h1, __half* __restrict__ h1s, int N) {
    __shared__ float w[F_IN * HID];
    __shared__ float rows[4][F_IN];
    int tid = threadIdx.x;
    for (int idx = tid; idx < F_IN * HID; idx += 256) w[idx] = W1[idx];
    int local = tid >> 6, f = tid & 63;
    int node = blockIdx.x * 4 + local;
    if (node < N && f < F_IN) rows[local][f] = aggx[node * F_IN + f];
    __syncthreads();
    if (node < N) {
        float acc = b1[f];
#pragma unroll
        for (int k = 0; k < F_IN; k++) acc += rows[local][k] * w[k * HID + f];
        float v = tanhf(acc);
        h1[node * HID + f] = v;
        h1s[node * HID + f] = __float2half(dinv[node] * v);
    }
}

// ---------- fused: layer-2 aggregation (half gather) + mm2 + tanh -> h2 (half) ----------
__global__ __launch_bounds__(256) void agg_h_mm2(
        const __half* __restrict__ h1s, const float* __restrict__ dinv,
        const int* __restrict__ rowptr, const int* __restrict__ ssrc,
        const float* __restrict__ W2, const float* __restrict__ b2,
        __half* __restrict__ h2, int N) {
    __shared__ float w[HID * HID];     // 16 KB
    __shared__ float aggl[4][HID];     // 1 KB
    int tid = threadIdx.x;
    for (int i = tid; i < HID * HID; i += 256) w[i] = W2[i];
    int wv = tid >> 6, f = tid & 63;
    int node = blockIdx.x * 4 + wv;
    float acc = 0.f;
    if (node < N) {
        float di = dinv[node];
        int p0 = rowptr[node], p1 = rowptr[node + 1];
        for (int base = p0; base < p1; base += 64) {
            int m = min(64, p1 - base);
            int jl = (base + f < p1) ? ssrc[base + f] : 0;
            for (int i = 0; i < m; ++i) {
                int j = __shfl(jl, i, 64);
                acc += __half2float(h1s[j * HID + f]);
            }
        }
        acc += __half2float(h1s[node * HID + f]);  // self-loop (prescaled)
        acc *= di;                                  // agg row, float
    }
    __syncthreads();                // W2 resident
    aggl[wv][f] = acc;
    __syncthreads();
    if (node < N) {
        float o = b2[f];
#pragma unroll 8
        for (int k = 0; k < HID; ++k) o += aggl[wv][k] * w[k * HID + f];
        h2[node * HID + f] = __float2half(tanhf(o));
    }
}

// ---------- pooled[g] = sum over nodes in graph g of [x, h1, h2] ----------
__device__ __forceinline__ int lower_bound_i(const int* b, int n, int v) {
    int lo = 0, hi = n;
    while (lo < hi) { int m = (lo + hi) >> 1; if (b[m] < v) lo = m + 1; else hi = m; }
    return lo;
}

__global__ void pool_kernel(const float* __restrict__ x, const float* __restrict__ h1,
                            const __half* __restrict__ h2, const int* __restrict__ batch,
                            float* __restrict__ pooled, int N) {
    int g = blockIdx.x >> 3;
    int sub = blockIdx.x & 7;
    int start = lower_bound_i(batch, N, g);
    int end = lower_bound_i(batch, N, g + 1);
    int len = end - start;
    int per = (len + 7) >> 3;
    int s = start + sub * per;
    int e = min(s + per, end);
    int f = threadIdx.x;
    if (f >= FC_DIM || s >= e) return;
    float acc = 0.f;
    if (f < F_IN) {
        for (int node = s; node < e; ++node) acc += x[node * F_IN + f];
    } else if (f < F_IN + HID) {
        int off = f - F_IN;
        for (int node = s; node < e; ++node) acc += h1[node * HID + off];
    } else {
        int off = f - F_IN - HID;
        for (int node = s; node < e; ++node) acc += __half2float(h2[node * HID + off]);
    }
    atomicAdd(&pooled[g * FC_DIM + f], acc);
}

// ---------- out = pooled @ fc_W^T + fc_b ----------
__global__ void fc_kernel(const float* __restrict__ pooled, const float* __restrict__ fcW,
                          const float* __restrict__ fcb, float* __restrict__ out) {
    __shared__ float p[FC_DIM];
    int g = blockIdx.x, tid = threadIdx.x;
    if (tid < FC_DIM) p[tid] = pooled[g * FC_DIM + tid];
    __syncthreads();
    if (tid < FC_DIM) {
        float acc = fcb[tid];
        for (int k = 0; k < FC_DIM; k++) acc += p[k] * fcW[tid * FC_DIM + k];
        out[g * FC_DIM + tid] = acc;
    }
}

extern "C" void kernel_launch(void* const* d_in, const int* in_sizes, int n_in,
                              void* d_out, int out_size, void* d_ws, size_t ws_size,
                              hipStream_t stream) {
    const float* x   = (const float*)d_in[0];
    const float* W1  = (const float*)d_in[1];
    const float* b1  = (const float*)d_in[2];
    const float* W2  = (const float*)d_in[3];
    const float* b2  = (const float*)d_in[4];
    const float* fcW = (const float*)d_in[5];
    const float* fcb = (const float*)d_in[6];
    const int*   ei  = (const int*)d_in[7];
    const int*   batch = (const int*)d_in[8];
    const int N = in_sizes[8];
    const int E = in_sizes[7] / 2;
    const int* src = ei;
    const int* dst = ei + E;

    char* ws = (char*)d_ws;
    size_t off = 0;
    auto alloc = [&](size_t bytes) -> void* {
        void* p = ws + off; off += (bytes + 255) & ~(size_t)255; return p;
    };
    int*    cnt    = (int*)alloc((size_t)N * 4);
    float*  dinv   = (float*)alloc((size_t)N * 4);
    int*    rowptr = (int*)alloc(((size_t)N + 1) * 4);
    int*    ssrc   = (int*)alloc((size_t)E * 4);
    __half* xs     = (__half*)alloc((size_t)N * F_IN * 2);
    float*  aggx   = (float*)alloc((size_t)N * F_IN * 4);
    float*  h1     = (float*)alloc((size_t)N * HID * 4);
    __half* h1s    = (__half*)alloc((size_t)N * HID * 2);
    __half* h2     = (__half*)alloc((size_t)N * HID * 2);
    float*  pooled = (float*)alloc((size_t)N_GRAPHS * FC_DIM * 4);
    float* out = (float*)d_out;

    hipMemsetAsync(cnt, 0, (size_t)N * 4, stream);
    hipMemsetAsync(pooled, 0, (size_t)N_GRAPHS * FC_DIM * 4, stream);

    count_deg<<<(E + 255) / 256, 256, 0, stream>>>(dst, E, cnt);
    dinv_xs<<<((size_t)N * 16 + 255) / 256, 256, 0, stream>>>(cnt, x, dinv, xs, N);
    scan_cnt<<<1, 1024, 0, stream>>>(cnt, rowptr, N);
    scatter_edges<<<(E + 255) / 256, 256, 0, stream>>>(src, dst, E, rowptr, cnt, ssrc);
    agg_x<<<((size_t)N * 16 + 255) / 256, 256, 0, stream>>>(xs, dinv, rowptr, ssrc, aggx, N);
    mm1<<<(N + 3) / 4, 256, 0, stream>>>(aggx, W1, b1, dinv, h1, h1s, N);
    agg_h_mm2<<<(N + 3) / 4, 256, 0, stream>>>(h1s, dinv, rowptr, ssrc, W2, b2, h2, N);
    pool_kernel<<<N_GRAPHS * 8, 192, 0, stream>>>(x, h1, h2, batch, pooled, N);
    fc_kernel<<<N_GRAPHS, 192, 0, stream>>>(pooled, fcW, fcb, out);
}

// Round 3
// 452.430 us; speedup vs baseline: 1.4408x; 1.2934x over previous
//
#include <hip/hip_runtime.h>
#include <hip/hip_fp16.h>
#include <math.h>

#define N_GRAPHS 256
#define F_IN 12
#define XS_STRIDE 16
#define HID 64
#define FC_DIM 140

#define SCAN_TPB 256
#define SCAN_VPT 16
#define SCAN_TILE (SCAN_TPB * SCAN_VPT)  // 4096

// ---------- degree count ----------
__global__ void count_deg(const int* __restrict__ dst, int E, int* __restrict__ cnt) {
    int e = blockIdx.x * blockDim.x + threadIdx.x;
    if (e < E) atomicAdd(&cnt[dst[e]], 1);
}

// ---------- dinv + prescaled half x table (padded to 16 halves = 32 B rows) ----------
__global__ void dinv_xs(const int* __restrict__ cnt, const float* __restrict__ x,
                        float* __restrict__ dinv, __half* __restrict__ xs, int N) {
    int t = blockIdx.x * blockDim.x + threadIdx.x;
    int node = t >> 4, f = t & 15;
    if (node >= N) return;
    float di = rsqrtf((float)(cnt[node] + 1));  // +1 self-loop
    if (f == 0) dinv[node] = di;
    float v = (f < F_IN) ? di * x[node * F_IN + f] : 0.f;
    xs[node * XS_STRIDE + f] = __float2half(v);
}

// ---------- 3-phase exclusive scan ----------
__global__ void scan1(const int* __restrict__ cnt, int* __restrict__ rowptr,
                      int* __restrict__ bsums, int n) {
    __shared__ int wsum[4];
    int tid = threadIdx.x, lane = tid & 63, wave = tid >> 6;
    int idx0 = blockIdx.x * SCAN_TILE + tid * SCAN_VPT;
    int v[SCAN_VPT]; int s = 0;
#pragma unroll
    for (int k = 0; k < SCAN_VPT; k++) { int i = idx0 + k; v[k] = (i < n) ? cnt[i] : 0; s += v[k]; }
    int incl = s;
#pragma unroll
    for (int off = 1; off < 64; off <<= 1) {
        int t = __shfl_up(incl, off, 64);
        if (lane >= off) incl += t;
    }
    if (lane == 63) wsum[wave] = incl;
    __syncthreads();
    int woff = 0;
#pragma unroll
    for (int w = 0; w < 4; w++) { int xv = wsum[w]; if (w < wave) woff += xv; }
    int run = woff + (incl - s);
#pragma unroll
    for (int k = 0; k < SCAN_VPT; k++) { int i = idx0 + k; if (i < n) rowptr[i] = run; run += v[k]; }
    if (tid == 0) bsums[blockIdx.x] = wsum[0] + wsum[1] + wsum[2] + wsum[3];
}

__global__ void scan2(int* __restrict__ bsums, int nb, int* __restrict__ rowptr_n) {
    __shared__ int wsum[16];
    int tid = threadIdx.x, lane = tid & 63, wave = tid >> 6;
    int v = (tid < nb) ? bsums[tid] : 0;
    int incl = v;
#pragma unroll
    for (int off = 1; off < 64; off <<= 1) {
        int t = __shfl_up(incl, off, 64);
        if (lane >= off) incl += t;
    }
    if (lane == 63) wsum[wave] = incl;
    __syncthreads();
    int woff = 0, total = 0;
#pragma unroll
    for (int w = 0; w < 16; w++) { int xv = wsum[w]; total += xv; if (w < wave) woff += xv; }
    if (tid < nb) bsums[tid] = woff + (incl - v);
    if (tid == 0) *rowptr_n = total;  // rowptr[n] = E
}

__global__ void scan3(int* __restrict__ rowptr, const int* __restrict__ bsums, int n) {
    int i = blockIdx.x * blockDim.x + threadIdx.x;
    if (i < n) rowptr[i] += bsums[i / SCAN_TILE];
}

// ---------- CSR scatter (consumes cnt as cursor via atomicSub) ----------
__global__ void scatter_edges(const int* __restrict__ src, const int* __restrict__ dst, int E,
                              const int* __restrict__ rowptr, int* __restrict__ cnt,
                              int* __restrict__ ssrc) {
    int e = blockIdx.x * blockDim.x + threadIdx.x;
    if (e < E) {
        int d = dst[e];
        int pos = rowptr[d] + (atomicSub(&cnt[d], 1) - 1);
        ssrc[pos] = src[e];
    }
}

// ---------- layer-1 aggregation (16 lanes/node, 8-way unrolled gather) ----------
__global__ void agg_x(const __half* __restrict__ xs, const float* __restrict__ dinv,
                      const int* __restrict__ rowptr, const int* __restrict__ ssrc,
                      float* __restrict__ aggx, int N) {
    int t = blockIdx.x * blockDim.x + threadIdx.x;
    int node = t >> 4;
    int f = t & 15;
    int gbase = (threadIdx.x & 63) & ~15;
    if (node >= N) return;
    float di = dinv[node];
    int p0 = rowptr[node], p1 = rowptr[node + 1];
    float acc = 0.f;
    for (int base = p0; base < p1; base += 16) {
        int m = min(16, p1 - base);
        int jl = (base + f < p1) ? ssrc[base + f] : 0;
        int i = 0;
        for (; i + 8 <= m; i += 8) {
            int j0 = __shfl(jl, gbase + i + 0, 64);
            int j1 = __shfl(jl, gbase + i + 1, 64);
            int j2 = __shfl(jl, gbase + i + 2, 64);
            int j3 = __shfl(jl, gbase + i + 3, 64);
            int j4 = __shfl(jl, gbase + i + 4, 64);
            int j5 = __shfl(jl, gbase + i + 5, 64);
            int j6 = __shfl(jl, gbase + i + 6, 64);
            int j7 = __shfl(jl, gbase + i + 7, 64);
            float v0 = __half2float(xs[j0 * XS_STRIDE + f]);
            float v1 = __half2float(xs[j1 * XS_STRIDE + f]);
            float v2 = __half2float(xs[j2 * XS_STRIDE + f]);
            float v3 = __half2float(xs[j3 * XS_STRIDE + f]);
            float v4 = __half2float(xs[j4 * XS_STRIDE + f]);
            float v5 = __half2float(xs[j5 * XS_STRIDE + f]);
            float v6 = __half2float(xs[j6 * XS_STRIDE + f]);
            float v7 = __half2float(xs[j7 * XS_STRIDE + f]);
            acc += ((v0 + v1) + (v2 + v3)) + ((v4 + v5) + (v6 + v7));
        }
        for (; i < m; ++i) {
            int j = __shfl(jl, gbase + i, 64);
            acc += __half2float(xs[j * XS_STRIDE + f]);
        }
    }
    acc += __half2float(xs[node * XS_STRIDE + f]);  // self-loop (prescaled)
    if (f < F_IN) aggx[node * F_IN + f] = di * acc;
}

// ---------- h1 = tanh(aggx @ W1 + b1); writes half h1h + half prescaled h1s ----------
__global__ void mm1(const float* __restrict__ aggx, const float* __restrict__ W1,
                    const float* __restrict__ b1, const float* __restrict__ dinv,
                    __half* __restrict__ h1h, __half* __restrict__ h1s, int N) {
    __shared__ float w[F_IN * HID];
    __shared__ float rows[4][F_IN];
    int tid = threadIdx.x;
    for (int idx = tid; idx < F_IN * HID; idx += 256) w[idx] = W1[idx];
    int local = tid >> 6, f = tid & 63;
    int node = blockIdx.x * 4 + local;
    if (node < N && f < F_IN) rows[local][f] = aggx[node * F_IN + f];
    __syncthreads();
    if (node < N) {
        float acc = b1[f];
#pragma unroll
        for (int k = 0; k < F_IN; k++) acc += rows[local][k] * w[k * HID + f];
        float v = tanhf(acc);
        h1h[node * HID + f] = __float2half(v);
        h1s[node * HID + f] = __float2half(dinv[node] * v);
    }
}

// ---------- fused: layer-2 aggregation (8-way unrolled) + mm2 + tanh -> h2 ----------
__global__ __launch_bounds__(256) void agg_h_mm2(
        const __half* __restrict__ h1s, const float* __restrict__ dinv,
        const int* __restrict__ rowptr, const int* __restrict__ ssrc,
        const float* __restrict__ W2, const float* __restrict__ b2,
        __half* __restrict__ h2, int N) {
    __shared__ float w[HID * HID];     // 16 KB
    __shared__ float aggl[4][HID];     // 1 KB
    int tid = threadIdx.x;
    for (int i = tid; i < HID * HID; i += 256) w[i] = W2[i];
    int wv = tid >> 6, f = tid & 63;
    int node = blockIdx.x * 4 + wv;
    float acc = 0.f;
    if (node < N) {
        float di = dinv[node];
        int p0 = rowptr[node], p1 = rowptr[node + 1];
        for (int base = p0; base < p1; base += 64) {
            int m = min(64, p1 - base);
            int jl = (base + f < p1) ? ssrc[base + f] : 0;
            int i = 0;
            for (; i + 8 <= m; i += 8) {
                int j0 = __shfl(jl, i + 0, 64);
                int j1 = __shfl(jl, i + 1, 64);
                int j2 = __shfl(jl, i + 2, 64);
                int j3 = __shfl(jl, i + 3, 64);
                int j4 = __shfl(jl, i + 4, 64);
                int j5 = __shfl(jl, i + 5, 64);
                int j6 = __shfl(jl, i + 6, 64);
                int j7 = __shfl(jl, i + 7, 64);
                float v0 = __half2float(h1s[j0 * HID + f]);
                float v1 = __half2float(h1s[j1 * HID + f]);
                float v2 = __half2float(h1s[j2 * HID + f]);
                float v3 = __half2float(h1s[j3 * HID + f]);
                float v4 = __half2float(h1s[j4 * HID + f]);
                float v5 = __half2float(h1s[j5 * HID + f]);
                float v6 = __half2float(h1s[j6 * HID + f]);
                float v7 = __half2float(h1s[j7 * HID + f]);
                acc += ((v0 + v1) + (v2 + v3)) + ((v4 + v5) + (v6 + v7));
            }
            for (; i < m; ++i) {
                int j = __shfl(jl, i, 64);
                acc += __half2float(h1s[j * HID + f]);
            }
        }
        acc += __half2float(h1s[node * HID + f]);  // self-loop (prescaled)
        acc *= di;
    }
    __syncthreads();                // W2 resident
    aggl[wv][f] = acc;
    __syncthreads();
    if (node < N) {
        float o = b2[f];
#pragma unroll 8
        for (int k = 0; k < HID; ++k) o += aggl[wv][k] * w[k * HID + f];
        h2[node * HID + f] = __float2half(tanhf(o));
    }
}

// ---------- pooled[g] = sum over nodes in graph g of [x, h1, h2] ----------
__device__ __forceinline__ int lower_bound_i(const int* b, int n, int v) {
    int lo = 0, hi = n;
    while (lo < hi) { int m = (lo + hi) >> 1; if (b[m] < v) lo = m + 1; else hi = m; }
    return lo;
}

__global__ void pool_kernel(const float* __restrict__ x, const __half* __restrict__ h1h,
                            const __half* __restrict__ h2, const int* __restrict__ batch,
                            float* __restrict__ pooled, int N) {
    int g = blockIdx.x >> 3;
    int sub = blockIdx.x & 7;
    int start = lower_bound_i(batch, N, g);
    int end = lower_bound_i(batch, N, g + 1);
    int len = end - start;
    int per = (len + 7) >> 3;
    int s = start + sub * per;
    int e = min(s + per, end);
    int f = threadIdx.x;
    if (f >= FC_DIM || s >= e) return;
    float acc = 0.f;
    if (f < F_IN) {
        for (int node = s; node < e; ++node) acc += x[node * F_IN + f];
    } else if (f < F_IN + HID) {
        int off = f - F_IN;
        for (int node = s; node < e; ++node) acc += __half2float(h1h[node * HID + off]);
    } else {
        int off = f - F_IN - HID;
        for (int node = s; node < e; ++node) acc += __half2float(h2[node * HID + off]);
    }
    atomicAdd(&pooled[g * FC_DIM + f], acc);
}

// ---------- out = pooled @ fc_W^T + fc_b ----------
__global__ void fc_kernel(const float* __restrict__ pooled, const float* __restrict__ fcW,
                          const float* __restrict__ fcb, float* __restrict__ out) {
    __shared__ float p[FC_DIM];
    int g = blockIdx.x, tid = threadIdx.x;
    if (tid < FC_DIM) p[tid] = pooled[g * FC_DIM + tid];
    __syncthreads();
    if (tid < FC_DIM) {
        float acc = fcb[tid];
        for (int k = 0; k < FC_DIM; k++) acc += p[k] * fcW[tid * FC_DIM + k];
        out[g * FC_DIM + tid] = acc;
    }
}

extern "C" void kernel_launch(void* const* d_in, const int* in_sizes, int n_in,
                              void* d_out, int out_size, void* d_ws, size_t ws_size,
                              hipStream_t stream) {
    const float* x   = (const float*)d_in[0];
    const float* W1  = (const float*)d_in[1];
    const float* b1  = (const float*)d_in[2];
    const float* W2  = (const float*)d_in[3];
    const float* b2  = (const float*)d_in[4];
    const float* fcW = (const float*)d_in[5];
    const float* fcb = (const float*)d_in[6];
    const int*   ei  = (const int*)d_in[7];
    const int*   batch = (const int*)d_in[8];
    const int N = in_sizes[8];
    const int E = in_sizes[7] / 2;
    const int* src = ei;
    const int* dst = ei + E;

    char* ws = (char*)d_ws;
    size_t off = 0;
    auto alloc = [&](size_t bytes) -> void* {
        void* p = ws + off; off += (bytes + 255) & ~(size_t)255; return p;
    };
    int*    cnt    = (int*)alloc((size_t)N * 4);
    float*  dinv   = (float*)alloc((size_t)N * 4);
    int*    rowptr = (int*)alloc(((size_t)N + 1) * 4);
    int*    bsums  = (int*)alloc(1024 * 4);
    int*    ssrc   = (int*)alloc((size_t)E * 4);
    __half* xs     = (__half*)alloc((size_t)N * XS_STRIDE * 2);
    float*  aggx   = (float*)alloc((size_t)N * F_IN * 4);
    __half* h1h    = (__half*)alloc((size_t)N * HID * 2);
    __half* h1s    = (__half*)alloc((size_t)N * HID * 2);
    __half* h2     = (__half*)alloc((size_t)N * HID * 2);
    float*  pooled = (float*)alloc((size_t)N_GRAPHS * FC_DIM * 4);
    float* out = (float*)d_out;

    hipMemsetAsync(cnt, 0, (size_t)N * 4, stream);
    hipMemsetAsync(pooled, 0, (size_t)N_GRAPHS * FC_DIM * 4, stream);

    const int nb = (N + SCAN_TILE - 1) / SCAN_TILE;

    count_deg<<<(E + 255) / 256, 256, 0, stream>>>(dst, E, cnt);
    dinv_xs<<<((size_t)N * 16 + 255) / 256, 256, 0, stream>>>(cnt, x, dinv, xs, N);
    scan1<<<nb, SCAN_TPB, 0, stream>>>(cnt, rowptr, bsums, N);
    scan2<<<1, 1024, 0, stream>>>(bsums, nb, rowptr + N);
    scan3<<<(N + 255) / 256, 256, 0, stream>>>(rowptr, bsums, N);
    scatter_edges<<<(E + 255) / 256, 256, 0, stream>>>(src, dst, E, rowptr, cnt, ssrc);
    agg_x<<<((size_t)N * 16 + 255) / 256, 256, 0, stream>>>(xs, dinv, rowptr, ssrc, aggx, N);
    mm1<<<(N + 3) / 4, 256, 0, stream>>>(aggx, W1, b1, dinv, h1h, h1s, N);
    agg_h_mm2<<<(N + 3) / 4, 256, 0, stream>>>(h1s, dinv, rowptr, ssrc, W2, b2, h2, N);
    pool_kernel<<<N_GRAPHS * 8, 192, 0, stream>>>(x, h1h, h2, batch, pooled, N);
    fc_kernel<<<N_GRAPHS, 192, 0, stream>>>(pooled, fcW, fcb, out);
}